// Round 1
// baseline (181.002 us; speedup 1.0000x reference)
//
#include <hip/hip_runtime.h>
#include <math.h>

#define H 512
#define W 512
#define IMG (H*W)
#define NIMG 32           // 16 images from y_hat + 16 from y
#define NSTRIP 10         // 56-col output strips per row
#define SW 56
#define RB 16             // output rows per band (halved: more waves for latency hiding)
#define NBAND 32          // 32*16 = 512 exactly
#define NPAIR (RB/2)      // steady row-pairs per wave
#define NHYST_BLK 1024

typedef unsigned long long u64;

__device__ __forceinline__ int reflect_idx(int i, int n) {
    if (i < 0) i = -i;
    if (i >= n) i = 2 * n - 2 - i;
    return i;
}

__device__ __forceinline__ float bperm_f(int addr, float v) {
    return __int_as_float(__builtin_amdgcn_ds_bpermute(addr, __float_as_int(v)));
}

// Composed 7-tap kernels: blur(5-tap gaussian) composed with sobel [1,2,1]/[-1,0,1].
#define S0 0.05448868454964294f
#define S1 0.35317871110251920f
#define S2 0.94551131545035710f
#define S3 1.29364257779496160f
#define A1 0.05448868454964294f
#define A2 0.24420134200323332f
#define A3 0.34813126234460456f

// ---------------------------------------------------------------------------
// Kernel 1 (line-scan, row-PAIR pipelined): one wave per (image,strip,band).
// Lane = gray col 56s-4+lane. Each iteration: consume 2 prefetched rows,
// prefetch next 2, 2 h-rows via 12 bpermutes, 2 mag rows, 2 NMS rows, one
// 16B paired store. Output: 56-bit words, plane[img][strip][row].
// RB=16 -> 10240 waves (40/CU avail, 32/CU resident at launch_bounds 8).
// ---------------------------------------------------------------------------
__global__ __launch_bounds__(256, 8) void k_edges(const float* __restrict__ yhat,
                                                  const float* __restrict__ yy,
                                                  u64* __restrict__ strongP,
                                                  u64* __restrict__ weakP,
                                                  unsigned int* __restrict__ counters) {
    const int wid = blockIdx.x * 4 + (threadIdx.x >> 6);
    const int lane = threadIdx.x & 63;

    // zero the fused-finalize counters for this iteration (k_hyst runs after us)
    if (wid == 0 && lane == 0) { counters[0] = 0u; counters[1] = 0u; }

    const int n = wid / (NSTRIP * NBAND);
    const int rem = wid - n * (NSTRIP * NBAND);
    const int s = rem / NBAND;
    const int band = rem - s * NBAND;
    const int y0 = band * RB;
    const float* src = (n < 16) ? (yhat + (size_t)n * 3 * IMG)
                                : (yy + (size_t)(n - 16) * 3 * IMG);

    const int c = s * SW - 4 + lane;
    const int cx = reflect_idx(c, W);
    const bool colok = ((unsigned)c < (unsigned)W);
    const u64 omask = (s == 9) ? 0xFFull : 0x00FFFFFFFFFFFFFFull;

    const int aM3 = ((lane - 3) << 2), aM2 = ((lane - 2) << 2), aM1 = ((lane - 1) << 2);
    const int aP1 = ((lane + 1) << 2), aP2 = ((lane + 2) << 2), aP3 = ((lane + 3) << 2);

    float hx[7], hy[7];
#pragma unroll
    for (int j = 0; j < 7; j++) { hx[j] = 0.f; hy[j] = 0.f; }

    const u64 outBase = ((size_t)n * NSTRIP + s) * H;

    // prefetched pair registers
    float r0, g0c, b0, r1, g1c, b1;
    {
        const float* p0 = src + (size_t)reflect_idx(y0 - 4, H) * W + cx;
        const float* p1 = src + (size_t)reflect_idx(y0 - 3, H) * W + cx;
        r0 = p0[0]; g0c = p0[IMG]; b0 = p0[2 * IMG];
        r1 = p1[0]; g1c = p1[IMG]; b1 = p1[2 * IMG];
    }

#define PREFETCH(k)                                                             \
    {                                                                           \
        const float* p0 = src + (size_t)reflect_idx(y0 - 4 + 2 * (k), H) * W + cx; \
        const float* p1 = src + (size_t)reflect_idx(y0 - 3 + 2 * (k), H) * W + cx; \
        r0 = p0[0]; g0c = p0[IMG]; b0 = p0[2 * IMG];                            \
        r1 = p1[0]; g1c = p1[IMG]; b1 = p1[2 * IMG];                            \
    }

#define HPUSH(gv)                                                               \
    {                                                                           \
        float gm1 = bperm_f(aM1, gv), gp1 = bperm_f(aP1, gv);                   \
        float gm2 = bperm_f(aM2, gv), gp2 = bperm_f(aP2, gv);                   \
        float gm3 = bperm_f(aM3, gv), gp3 = bperm_f(aP3, gv);                   \
        _Pragma("unroll")                                                       \
        for (int j = 0; j < 6; j++) { hx[j] = hx[j + 1]; hy[j] = hy[j + 1]; }   \
        hx[6] = A3 * (gp1 - gm1) + A2 * (gp2 - gm2) + A1 * (gp3 - gm3);         \
        hy[6] = S3 * gv + S2 * (gp1 + gm1) + S1 * (gp2 + gm2) + S0 * (gp3 + gm3); \
    }

    // MAG computes mag^2 + L/R + dir for FIFO-center row `mr`
#define MAG(mr, mv, mvL, mvR, dv)                                               \
    {                                                                           \
        float gx = S3 * hx[3] + S2 * (hx[4] + hx[2])                            \
                 + S1 * (hx[5] + hx[1]) + S0 * (hx[6] + hx[0]);                 \
        float gy = A3 * (hy[4] - hy[2]) + A2 * (hy[5] - hy[1])                  \
                 + A1 * (hy[6] - hy[0]);                                        \
        bool okm = colok && ((unsigned)(mr) < (unsigned)H);                     \
        mv = okm ? (gx * gx + gy * gy + 1e-12f) : 0.f;                          \
        mvL = bperm_f(aM1, mv);                                                 \
        mvR = bperm_f(aP1, mv);                                                 \
        float ax = fabsf(gx), ay = fabsf(gy);                                   \
        dv = (ay <= 0.4142135623730951f * ax) ? 0                               \
           : (ay >= 2.414213562373095f * ax) ? 2                                \
           : (((gx > 0.f) == (gy > 0.f)) ? 1 : 3);                              \
    }

    // ---- prime: pairs 0..2 fill FIFO (gray rows y0-4 .. y0+1) ----
#pragma unroll
    for (int k = 0; k < 3; k++) {
        float ga = 0.299f * r0 + 0.587f * g0c + 0.114f * b0;
        float gb = 0.299f * r1 + 0.587f * g1c + 0.114f * b1;
        PREFETCH(k + 1);
        HPUSH(ga);
        HPUSH(gb);
    }

    // pair 3: gray rows y0+2,y0+3 -> mag rows y0-1, y0
    float mm1, mm1L, mm1R, m0, m0L, m0R;
    int dir0;
    {
        float ga = 0.299f * r0 + 0.587f * g0c + 0.114f * b0;
        float gb = 0.299f * r1 + 0.587f * g1c + 0.114f * b1;
        PREFETCH(4);
        int dtmp;
        HPUSH(ga);
        MAG(y0 - 1, mm1, mm1L, mm1R, dtmp);
        (void)dtmp;
        HPUSH(gb);
        MAG(y0, m0, m0L, m0R, dir0);
    }

    // ---- steady: pairs k=4..4+NPAIR-1; outputs rows t0=y0+2k-8, t1=t0+1 ----
#pragma unroll 4
    for (int k = 4; k < 4 + NPAIR; k++) {
        float ga = 0.299f * r0 + 0.587f * g0c + 0.114f * b0;
        float gb = 0.299f * r1 + 0.587f * g1c + 0.114f * b1;
        if (k < 3 + NPAIR) PREFETCH(k + 1);

        float ma, maL, maR, mb, mbL, mbR;
        int da, db;
        HPUSH(ga);
        MAG(y0 + 2 * k - 7, ma, maL, maR, da);
        HPUSH(gb);
        MAG(y0 + 2 * k - 6, mb, mbL, mbR, db);

        // row t0: mags (mm1, m0, ma), dir0
        float n1 = (dir0 == 0) ? m0R : (dir0 == 1) ? maR : (dir0 == 2) ? ma : maL;
        float n2 = (dir0 == 0) ? m0L : (dir0 == 1) ? mm1L : (dir0 == 2) ? mm1 : mm1R;
        bool ok0 = (m0 >= n1) && (m0 >= n2);
        u64 bs0 = __ballot(ok0 && (m0 >= 0.04f));
        u64 bw0 = __ballot(ok0 && (m0 >= 0.01f));

        // row t1: mags (m0, ma, mb), dir = da
        float n3 = (da == 0) ? maR : (da == 1) ? mbR : (da == 2) ? mb : mbL;
        float n4 = (da == 0) ? maL : (da == 1) ? m0L : (da == 2) ? m0 : m0R;
        bool ok1 = (ma >= n3) && (ma >= n4);
        u64 bs1 = __ballot(ok1 && (ma >= 0.04f));
        u64 bw1 = __ballot(ok1 && (ma >= 0.01f));

        if (lane == 0) {
            int t0 = y0 + 2 * k - 8;
            ulonglong2 vs, vw;
            vs.x = (bs0 >> 4) & omask; vs.y = (bs1 >> 4) & omask;
            vw.x = (bw0 >> 4) & omask; vw.y = (bw1 >> 4) & omask;
            *(ulonglong2*)&strongP[outBase + t0] = vs;
            *(ulonglong2*)&weakP[outBase + t0] = vw;
        }

        mm1 = ma; mm1L = maL; mm1R = maR;
        m0 = mb; m0L = mbL; m0R = mbR;
        dir0 = db;
    }
#undef PREFETCH
#undef HPUSH
#undef MAG
}

// ---------------------------------------------------------------------------
// Kernel 2: bit-parallel hysteresis (10 iters, exact via light cone) + diff
// count + fused final reduction (atomic counter + ticket, last block writes).
// One wave per 32x32 tile per image-pair; lane l = row ty0-10+l.
// Loads from 56-bit strip words via 3-word funnel shift.
// ---------------------------------------------------------------------------
__device__ __forceinline__ u64 ldw10(const u64* p, int img, int y, int q, bool ok) {
    return (ok && q >= 0 && q < NSTRIP) ? p[((size_t)img * NSTRIP + q) * H + y] : 0ULL;
}

__global__ __launch_bounds__(256) void k_hyst(const u64* __restrict__ strongP,
                                              const u64* __restrict__ weakP,
                                              unsigned int* __restrict__ counters,
                                              float* __restrict__ out) {
    __shared__ unsigned int part[4];
    const int wy = threadIdx.x >> 6;
    const int wave = blockIdx.x * 4 + wy;
    const int lane = threadIdx.x & 63;
    const int tile = wave & 255;
    const int pair = wave >> 8;          // 0..15
    const int tx0 = (tile & 15) * 32;
    const int ty0 = (tile >> 4) * 32;

    const int y = ty0 - 10 + lane;
    const bool rowok = (lane < 52) && (y >= 0) && (y < H);
    const int yc = rowok ? y : 0;

    const int x = tx0 - 10;
    const int q0 = (x < 0) ? -1 : (x / 56);
    const int r = x - 56 * q0;           // 1..55, never 0
    const int sh1 = 56 - r;
    const bool need3 = (r > 48);
    const int sh2 = 112 - r;

    const int imgA = pair, imgB = pair + 16;
    u64 sA, wA, sB, wB;
    {
        u64 w0, w1, w2;
        w0 = ldw10(strongP, imgA, yc, q0, rowok);
        w1 = ldw10(strongP, imgA, yc, q0 + 1, rowok);
        w2 = need3 ? ldw10(strongP, imgA, yc, q0 + 2, rowok) : 0ULL;
        sA = (w0 >> r) | (w1 << sh1) | (need3 ? (w2 << sh2) : 0ULL);
        w0 = ldw10(weakP, imgA, yc, q0, rowok);
        w1 = ldw10(weakP, imgA, yc, q0 + 1, rowok);
        w2 = need3 ? ldw10(weakP, imgA, yc, q0 + 2, rowok) : 0ULL;
        wA = (w0 >> r) | (w1 << sh1) | (need3 ? (w2 << sh2) : 0ULL);
        w0 = ldw10(strongP, imgB, yc, q0, rowok);
        w1 = ldw10(strongP, imgB, yc, q0 + 1, rowok);
        w2 = need3 ? ldw10(strongP, imgB, yc, q0 + 2, rowok) : 0ULL;
        sB = (w0 >> r) | (w1 << sh1) | (need3 ? (w2 << sh2) : 0ULL);
        w0 = ldw10(weakP, imgB, yc, q0, rowok);
        w1 = ldw10(weakP, imgB, yc, q0 + 1, rowok);
        w2 = need3 ? ldw10(weakP, imgB, yc, q0 + 2, rowok) : 0ULL;
        wB = (w0 >> r) | (w1 << sh1) | (need3 ? (w2 << sh2) : 0ULL);
    }

#pragma unroll
    for (int it = 0; it < 10; it++) {
        u64 up = __shfl_up(sA, 1), dn = __shfl_down(sA, 1);
        u64 t = up | sA | dn;
        sA |= (t | (t << 1) | (t >> 1)) & wA;
        up = __shfl_up(sB, 1); dn = __shfl_down(sB, 1);
        t = up | sB | dn;
        sB |= (t | (t << 1) | (t >> 1)) & wB;
    }

    unsigned int cgt = 0;
    if (lane >= 10 && lane < 42) {
        const u64 mask = ((1ULL << 42) - (1ULL << 10));
        cgt = (unsigned int)__popcll((sA ^ sB) & mask);
    }
#pragma unroll
    for (int off = 32; off > 0; off >>= 1) cgt += __shfl_down(cgt, off);
    if (lane == 0) part[wy] = cgt;
    __syncthreads();
    if (threadIdx.x == 0) {
        unsigned int tot = part[0] + part[1] + part[2] + part[3];
        atomicAdd(&counters[0], tot);
        __threadfence();
        unsigned int t = atomicAdd(&counters[1], 1u);
        if (t == NHYST_BLK - 1) {
            unsigned int total = atomicAdd(&counters[0], 0u);  // all adds visible
            out[0] = (float)total * (1.0f / 4194304.0f);
        }
    }
}

extern "C" void kernel_launch(void* const* d_in, const int* in_sizes, int n_in,
                              void* d_out, int out_size, void* d_ws, size_t ws_size,
                              hipStream_t stream) {
    const float* yhat = (const float*)d_in[0];
    const float* yy = (const float*)d_in[1];

    u64* strongP = (u64*)d_ws;                        // 32*10*512 u64 = 1.31 MB
    u64* weakP = strongP + (size_t)NIMG * NSTRIP * H; // 1.31 MB
    unsigned int* counters = (unsigned int*)(weakP + (size_t)NIMG * NSTRIP * H);

    // 32 img x 10 strips x 32 bands = 10240 waves, 4 waves/block
    k_edges<<<2560, 256, 0, stream>>>(yhat, yy, strongP, weakP, counters);

    // 256 tiles x 16 pairs = 4096 waves, 4 waves/block; fused finalize
    k_hyst<<<1024, 256, 0, stream>>>(strongP, weakP, counters, (float*)d_out);
}

// Round 2
// 155.563 us; speedup vs baseline: 1.1635x; 1.1635x over previous
//
#include <hip/hip_runtime.h>
#include <math.h>

#define H 512
#define W 512
#define IMG (H*W)
#define NIMG 32           // 16 images from y_hat + 16 from y
#define NSTRIP 10         // 56-col output strips per row
#define SW 56
#define RB 32             // output rows per band (round-0 shape: one cohort, 5 blk/CU)
#define NBAND 16          // 16*32 = 512 exactly
#define NPAIR (RB/2)
#define NHYST_BLK 1024

typedef unsigned long long u64;

__device__ __forceinline__ int reflect_idx(int i, int n) {
    if (i < 0) i = -i;
    if (i >= n) i = 2 * n - 2 - i;
    return i;
}

// DPP full-wave lane shifts (VALU pipe — replaces ds_bpermute, no lgkmcnt).
// wave_shr:1 (0x138): lane i <- lane i-1 ; wave_shl:1 (0x130): lane i <- lane i+1.
// bound_ctrl=true: out-of-range lanes read 0 (only halo lanes, outputs discarded).
__device__ __forceinline__ float dpp_shr1(float v) {
    return __int_as_float(__builtin_amdgcn_update_dpp(
        0, __float_as_int(v), 0x138, 0xF, 0xF, true));
}
__device__ __forceinline__ float dpp_shl1(float v) {
    return __int_as_float(__builtin_amdgcn_update_dpp(
        0, __float_as_int(v), 0x130, 0xF, 0xF, true));
}

// Composed 7-tap kernels: blur(5-tap gaussian) composed with sobel [1,2,1]/[-1,0,1].
#define S0 0.05448868454964294f
#define S1 0.35317871110251920f
#define S2 0.94551131545035710f
#define S3 1.29364257779496160f
#define A1 0.05448868454964294f
#define A2 0.24420134200323332f
#define A3 0.34813126234460456f

// ---------------------------------------------------------------------------
// Kernel 1 (line-scan, row-PAIR pipelined): one wave per (image,strip,band).
// Lane = gray col 56s-4+lane. Each iteration: consume 2 prefetched rows,
// prefetch next 2, 2 h-rows via 12 DPP shifts, 2 mag rows (+4 DPP), 2 NMS
// rows, one 16B paired store. Output: 56-bit words, plane[img][strip][row].
// ---------------------------------------------------------------------------
__global__ __launch_bounds__(256, 5) void k_edges(const float* __restrict__ yhat,
                                                  const float* __restrict__ yy,
                                                  u64* __restrict__ strongP,
                                                  u64* __restrict__ weakP,
                                                  unsigned int* __restrict__ counters) {
    const int wid = blockIdx.x * 4 + (threadIdx.x >> 6);
    const int lane = threadIdx.x & 63;

    // zero the fused-finalize counters (k_hyst runs after us in-stream)
    if (wid == 0 && lane == 0) { counters[0] = 0u; counters[1] = 0u; }

    const int n = wid / (NSTRIP * NBAND);
    const int rem = wid - n * (NSTRIP * NBAND);
    const int s = rem / NBAND;
    const int band = rem - s * NBAND;
    const int y0 = band * RB;
    const float* src = (n < 16) ? (yhat + (size_t)n * 3 * IMG)
                                : (yy + (size_t)(n - 16) * 3 * IMG);

    const int c = s * SW - 4 + lane;
    const int cx = reflect_idx(c, W);
    const bool colok = ((unsigned)c < (unsigned)W);
    const u64 omask = (s == 9) ? 0xFFull : 0x00FFFFFFFFFFFFFFull;

    float hx[7], hy[7];
#pragma unroll
    for (int j = 0; j < 7; j++) { hx[j] = 0.f; hy[j] = 0.f; }

    const u64 outBase = ((size_t)n * NSTRIP + s) * H;

    // prefetched pair registers
    float r0, g0c, b0, r1, g1c, b1;
    {
        const float* p0 = src + (size_t)reflect_idx(y0 - 4, H) * W + cx;
        const float* p1 = src + (size_t)reflect_idx(y0 - 3, H) * W + cx;
        r0 = p0[0]; g0c = p0[IMG]; b0 = p0[2 * IMG];
        r1 = p1[0]; g1c = p1[IMG]; b1 = p1[2 * IMG];
    }

#define PREFETCH(k)                                                             \
    {                                                                           \
        const float* p0 = src + (size_t)reflect_idx(y0 - 4 + 2 * (k), H) * W + cx; \
        const float* p1 = src + (size_t)reflect_idx(y0 - 3 + 2 * (k), H) * W + cx; \
        r0 = p0[0]; g0c = p0[IMG]; b0 = p0[2 * IMG];                            \
        r1 = p1[0]; g1c = p1[IMG]; b1 = p1[2 * IMG];                            \
    }

#define HPUSH(gv)                                                               \
    {                                                                           \
        float gm1 = dpp_shr1(gv), gp1 = dpp_shl1(gv);                           \
        float gm2 = dpp_shr1(gm1), gp2 = dpp_shl1(gp1);                         \
        float gm3 = dpp_shr1(gm2), gp3 = dpp_shl1(gp2);                         \
        _Pragma("unroll")                                                       \
        for (int j = 0; j < 6; j++) { hx[j] = hx[j + 1]; hy[j] = hy[j + 1]; }   \
        hx[6] = A3 * (gp1 - gm1) + A2 * (gp2 - gm2) + A1 * (gp3 - gm3);         \
        hy[6] = S3 * gv + S2 * (gp1 + gm1) + S1 * (gp2 + gm2) + S0 * (gp3 + gm3); \
    }

    // MAG computes mag^2 + L/R + dir for FIFO-center row `mr`
#define MAG(mr, mv, mvL, mvR, dv)                                               \
    {                                                                           \
        float gx = S3 * hx[3] + S2 * (hx[4] + hx[2])                            \
                 + S1 * (hx[5] + hx[1]) + S0 * (hx[6] + hx[0]);                 \
        float gy = A3 * (hy[4] - hy[2]) + A2 * (hy[5] - hy[1])                  \
                 + A1 * (hy[6] - hy[0]);                                        \
        bool okm = colok && ((unsigned)(mr) < (unsigned)H);                     \
        mv = okm ? (gx * gx + gy * gy + 1e-12f) : 0.f;                          \
        mvL = dpp_shr1(mv);                                                     \
        mvR = dpp_shl1(mv);                                                     \
        float ax = fabsf(gx), ay = fabsf(gy);                                   \
        dv = (ay <= 0.4142135623730951f * ax) ? 0                               \
           : (ay >= 2.414213562373095f * ax) ? 2                                \
           : (((gx > 0.f) == (gy > 0.f)) ? 1 : 3);                              \
    }

    // ---- prime: pairs 0..2 fill FIFO (gray rows y0-4 .. y0+1) ----
#pragma unroll
    for (int k = 0; k < 3; k++) {
        float ga = 0.299f * r0 + 0.587f * g0c + 0.114f * b0;
        float gb = 0.299f * r1 + 0.587f * g1c + 0.114f * b1;
        PREFETCH(k + 1);
        HPUSH(ga);
        HPUSH(gb);
    }

    // pair 3: gray rows y0+2,y0+3 -> mag rows y0-1, y0
    float mm1, mm1L, mm1R, m0, m0L, m0R;
    int dir0;
    {
        float ga = 0.299f * r0 + 0.587f * g0c + 0.114f * b0;
        float gb = 0.299f * r1 + 0.587f * g1c + 0.114f * b1;
        PREFETCH(4);
        int dtmp;
        HPUSH(ga);
        MAG(y0 - 1, mm1, mm1L, mm1R, dtmp);
        (void)dtmp;
        HPUSH(gb);
        MAG(y0, m0, m0L, m0R, dir0);
    }

    // ---- steady: pairs k=4..19; outputs rows t0=y0+2k-8, t1=t0+1 ----
#pragma unroll 4
    for (int k = 4; k < 4 + NPAIR; k++) {
        float ga = 0.299f * r0 + 0.587f * g0c + 0.114f * b0;
        float gb = 0.299f * r1 + 0.587f * g1c + 0.114f * b1;
        if (k < 3 + NPAIR) PREFETCH(k + 1);

        float ma, maL, maR, mb, mbL, mbR;
        int da, db;
        HPUSH(ga);
        MAG(y0 + 2 * k - 7, ma, maL, maR, da);
        HPUSH(gb);
        MAG(y0 + 2 * k - 6, mb, mbL, mbR, db);

        // row t0: mags (mm1, m0, ma), dir0
        float n1 = (dir0 == 0) ? m0R : (dir0 == 1) ? maR : (dir0 == 2) ? ma : maL;
        float n2 = (dir0 == 0) ? m0L : (dir0 == 1) ? mm1L : (dir0 == 2) ? mm1 : mm1R;
        bool ok0 = (m0 >= n1) && (m0 >= n2);
        u64 bs0 = __ballot(ok0 && (m0 >= 0.04f));
        u64 bw0 = __ballot(ok0 && (m0 >= 0.01f));

        // row t1: mags (m0, ma, mb), dir = da
        float n3 = (da == 0) ? maR : (da == 1) ? mbR : (da == 2) ? mb : mbL;
        float n4 = (da == 0) ? maL : (da == 1) ? m0L : (da == 2) ? m0 : m0R;
        bool ok1 = (ma >= n3) && (ma >= n4);
        u64 bs1 = __ballot(ok1 && (ma >= 0.04f));
        u64 bw1 = __ballot(ok1 && (ma >= 0.01f));

        if (lane == 0) {
            int t0 = y0 + 2 * k - 8;
            ulonglong2 vs, vw;
            vs.x = (bs0 >> 4) & omask; vs.y = (bs1 >> 4) & omask;
            vw.x = (bw0 >> 4) & omask; vw.y = (bw1 >> 4) & omask;
            *(ulonglong2*)&strongP[outBase + t0] = vs;
            *(ulonglong2*)&weakP[outBase + t0] = vw;
        }

        mm1 = ma; mm1L = maL; mm1R = maR;
        m0 = mb; m0L = mbL; m0R = mbR;
        dir0 = db;
    }
#undef PREFETCH
#undef HPUSH
#undef MAG
}

// ---------------------------------------------------------------------------
// Kernel 2: bit-parallel hysteresis (10 iters, exact via light cone) + diff
// count + fused final reduction (atomic counter + ticket, last block writes).
// One wave per 32x32 tile per image-pair; lane l = row ty0-10+l.
// Loads from 56-bit strip words via 3-word funnel shift (coalesced: lane=y).
// ---------------------------------------------------------------------------
__device__ __forceinline__ u64 ldw10(const u64* p, int img, int y, int q, bool ok) {
    return (ok && q >= 0 && q < NSTRIP) ? p[((size_t)img * NSTRIP + q) * H + y] : 0ULL;
}

__global__ __launch_bounds__(256) void k_hyst(const u64* __restrict__ strongP,
                                              const u64* __restrict__ weakP,
                                              unsigned int* __restrict__ counters,
                                              float* __restrict__ out) {
    __shared__ unsigned int part[4];
    const int wy = threadIdx.x >> 6;
    const int wave = blockIdx.x * 4 + wy;
    const int lane = threadIdx.x & 63;
    const int tile = wave & 255;
    const int pair = wave >> 8;          // 0..15
    const int tx0 = (tile & 15) * 32;
    const int ty0 = (tile >> 4) * 32;

    const int y = ty0 - 10 + lane;
    const bool rowok = (lane < 52) && (y >= 0) && (y < H);
    const int yc = rowok ? y : 0;

    const int x = tx0 - 10;
    const int q0 = (x < 0) ? -1 : (x / 56);
    const int r = x - 56 * q0;           // 1..55, never 0
    const int sh1 = 56 - r;
    const bool need3 = (r > 48);
    const int sh2 = 112 - r;

    const int imgA = pair, imgB = pair + 16;
    u64 sA, wA, sB, wB;
    {
        u64 w0, w1, w2;
        w0 = ldw10(strongP, imgA, yc, q0, rowok);
        w1 = ldw10(strongP, imgA, yc, q0 + 1, rowok);
        w2 = need3 ? ldw10(strongP, imgA, yc, q0 + 2, rowok) : 0ULL;
        sA = (w0 >> r) | (w1 << sh1) | (need3 ? (w2 << sh2) : 0ULL);
        w0 = ldw10(weakP, imgA, yc, q0, rowok);
        w1 = ldw10(weakP, imgA, yc, q0 + 1, rowok);
        w2 = need3 ? ldw10(weakP, imgA, yc, q0 + 2, rowok) : 0ULL;
        wA = (w0 >> r) | (w1 << sh1) | (need3 ? (w2 << sh2) : 0ULL);
        w0 = ldw10(strongP, imgB, yc, q0, rowok);
        w1 = ldw10(strongP, imgB, yc, q0 + 1, rowok);
        w2 = need3 ? ldw10(strongP, imgB, yc, q0 + 2, rowok) : 0ULL;
        sB = (w0 >> r) | (w1 << sh1) | (need3 ? (w2 << sh2) : 0ULL);
        w0 = ldw10(weakP, imgB, yc, q0, rowok);
        w1 = ldw10(weakP, imgB, yc, q0 + 1, rowok);
        w2 = need3 ? ldw10(weakP, imgB, yc, q0 + 2, rowok) : 0ULL;
        wB = (w0 >> r) | (w1 << sh1) | (need3 ? (w2 << sh2) : 0ULL);
    }

#pragma unroll
    for (int it = 0; it < 10; it++) {
        u64 up = __shfl_up(sA, 1), dn = __shfl_down(sA, 1);
        u64 t = up | sA | dn;
        sA |= (t | (t << 1) | (t >> 1)) & wA;
        up = __shfl_up(sB, 1); dn = __shfl_down(sB, 1);
        t = up | sB | dn;
        sB |= (t | (t << 1) | (t >> 1)) & wB;
    }

    unsigned int cgt = 0;
    if (lane >= 10 && lane < 42) {
        const u64 mask = ((1ULL << 42) - (1ULL << 10));
        cgt = (unsigned int)__popcll((sA ^ sB) & mask);
    }
#pragma unroll
    for (int off = 32; off > 0; off >>= 1) cgt += __shfl_down(cgt, off);
    if (lane == 0) part[wy] = cgt;
    __syncthreads();
    if (threadIdx.x == 0) {
        unsigned int tot = part[0] + part[1] + part[2] + part[3];
        atomicAdd(&counters[0], tot);
        __threadfence();
        unsigned int t = atomicAdd(&counters[1], 1u);
        if (t == NHYST_BLK - 1) {
            unsigned int total = atomicAdd(&counters[0], 0u);  // all adds visible
            out[0] = (float)total * (1.0f / 4194304.0f);
        }
    }
}

extern "C" void kernel_launch(void* const* d_in, const int* in_sizes, int n_in,
                              void* d_out, int out_size, void* d_ws, size_t ws_size,
                              hipStream_t stream) {
    const float* yhat = (const float*)d_in[0];
    const float* yy = (const float*)d_in[1];

    u64* strongP = (u64*)d_ws;                        // 32*10*512 u64 = 1.31 MB
    u64* weakP = strongP + (size_t)NIMG * NSTRIP * H; // 1.31 MB
    unsigned int* counters = (unsigned int*)(weakP + (size_t)NIMG * NSTRIP * H);

    // 32 img x 10 strips x 16 bands = 5120 waves, 4 waves/block, 5 blk/CU
    k_edges<<<1280, 256, 0, stream>>>(yhat, yy, strongP, weakP, counters);

    // 256 tiles x 16 pairs = 4096 waves, 4 waves/block; fused finalize
    k_hyst<<<1024, 256, 0, stream>>>(strongP, weakP, counters, (float*)d_out);
}

// Round 3
// 154.779 us; speedup vs baseline: 1.1694x; 1.0051x over previous
//
#include <hip/hip_runtime.h>
#include <math.h>

#define H 512
#define W 512
#define IMG (H*W)
#define NIMG 32           // 16 images from y_hat + 16 from y
#define NSTRIP 10         // 56-col output strips per row
#define SW 56
#define RB 32             // output rows per band (one cohort: 5120 waves, 5 blk/CU)
#define NBAND 16          // 16*32 = 512 exactly
#define NHYST_BLK 1024

typedef unsigned long long u64;

__device__ __forceinline__ int reflect_idx(int i, int n) {
    if (i < 0) i = -i;
    if (i >= n) i = 2 * n - 2 - i;
    return i;
}

__device__ __forceinline__ float bperm_f(int addr, float v) {
    return __int_as_float(__builtin_amdgcn_ds_bpermute(addr, __float_as_int(v)));
}

// DPP full-wave lane shifts (VALU pipe, single instr, no lgkmcnt).
// wave_shr:1 (0x138): lane i <- lane i-1 ; wave_shl:1 (0x130): lane i <- lane i+1.
// bound_ctrl=true: edge lanes read 0 — only halo lanes, outputs discarded.
__device__ __forceinline__ float dpp_shr1(float v) {
    return __int_as_float(__builtin_amdgcn_update_dpp(
        0, __float_as_int(v), 0x138, 0xF, 0xF, true));
}
__device__ __forceinline__ float dpp_shl1(float v) {
    return __int_as_float(__builtin_amdgcn_update_dpp(
        0, __float_as_int(v), 0x130, 0xF, 0xF, true));
}

// Composed 7-tap kernels: blur(5-tap gaussian) composed with sobel [1,2,1]/[-1,0,1].
#define S0c 0.05448868454964294f
#define S1c 0.35317871110251920f
#define S2c 0.94551131545035710f
#define S3c 1.29364257779496160f
#define A1c 0.05448868454964294f
#define A2c 0.24420134200323332f
#define A3c 0.34813126234460456f

// ---------------------------------------------------------------------------
// Kernel 1 (line-scan, row-PAIR pipelined): one wave per (image,strip,band).
// Lane = gray col 56s-4+lane. Ring-buffer h-FIFO (depth 8, compile-time
// indices -> zero movs). Shuffles: +-1 via DPP (VALU), +-2/3 via bperm (DS)
// — both un-chained from gv so the pipes overlap. Scalarized addressing
// (readfirstlane -> SGPR bases + 32-bit voffset). Output: 56-bit words,
// plane[img][strip][row].
// ---------------------------------------------------------------------------
__global__ __launch_bounds__(256, 5) void k_edges(const float* __restrict__ yhat,
                                                  const float* __restrict__ yy,
                                                  u64* __restrict__ strongP,
                                                  u64* __restrict__ weakP,
                                                  unsigned int* __restrict__ counters) {
    const int widv = blockIdx.x * 4 + (threadIdx.x >> 6);
    const int wid = __builtin_amdgcn_readfirstlane(widv);   // wave-uniform -> SGPR
    const int lane = threadIdx.x & 63;

    // zero the fused-finalize counters (k_hyst runs after us in-stream)
    if (wid == 0 && lane == 0) { counters[0] = 0u; counters[1] = 0u; }

    const int n = wid / (NSTRIP * NBAND);
    const int rem = wid - n * (NSTRIP * NBAND);
    const int s = rem / NBAND;
    const int band = rem - s * NBAND;
    const int y0 = band * RB;
    const float* src = (n < 16) ? (yhat + (size_t)n * 3 * IMG)
                                : (yy + (size_t)(n - 16) * 3 * IMG);
    const float* __restrict__ srcR = src;
    const float* __restrict__ srcG = src + IMG;
    const float* __restrict__ srcB = src + 2 * IMG;

    const int c = s * SW - 4 + lane;
    const int cx = reflect_idx(c, W);
    const bool colok = ((unsigned)c < (unsigned)W);
    const u64 omask = (s == 9) ? 0xFFull : 0x00FFFFFFFFFFFFFFull;

    const int aM3 = ((lane - 3) << 2), aM2 = ((lane - 2) << 2);
    const int aP2 = ((lane + 2) << 2), aP3 = ((lane + 3) << 2);

    float hx[8], hy[8];
#pragma unroll
    for (int j = 0; j < 8; j++) { hx[j] = 0.f; hy[j] = 0.f; }

    const u64 outBase = ((size_t)n * NSTRIP + s) * H;

    // prefetched pair registers
    float r0, g0c, b0, r1, g1c, b1;

    // rows y0-4+2k, y0-3+2k; branchless reflect: min(abs(y), 1022-abs(y))
#define LOADPAIR(kk)                                                            \
    {                                                                           \
        int ya = y0 - 4 + 2 * (kk), yb = ya + 1;                                \
        int aa = ya < 0 ? -ya : ya;  aa = aa < (1022 - aa) ? aa : (1022 - aa);  \
        int ab = yb < 0 ? -yb : yb;  ab = ab < (1022 - ab) ? ab : (1022 - ab);  \
        int voa = (aa << 9) + cx, vob = (ab << 9) + cx;                         \
        r0 = srcR[voa]; g0c = srcG[voa]; b0 = srcB[voa];                        \
        r1 = srcR[vob]; g1c = srcG[vob]; b1 = srcB[vob];                        \
    }

    // push gray row gv into ring slot P (P compile-time literal)
#define HPUSH_AT(gv, P)                                                         \
    {                                                                           \
        float gm1 = dpp_shr1(gv), gp1 = dpp_shl1(gv);                           \
        float gm2 = bperm_f(aM2, gv), gp2 = bperm_f(aP2, gv);                   \
        float gm3 = bperm_f(aM3, gv), gp3 = bperm_f(aP3, gv);                   \
        hx[(P) & 7] = A3c * (gp1 - gm1) + A2c * (gp2 - gm2) + A1c * (gp3 - gm3);\
        hy[(P) & 7] = S3c * gv + S2c * (gp1 + gm1) + S1c * (gp2 + gm2)          \
                    + S0c * (gp3 + gm3);                                        \
    }

    // mag^2 + L/R + dir for ring center CP (compile-time); okm gates validity
#define MAG_AT(CP, okm, mv, mvL, mvR, dv)                                       \
    {                                                                           \
        float gx = S3c * hx[(CP) & 7]                                           \
                 + S2c * (hx[((CP) + 1) & 7] + hx[((CP) + 7) & 7])              \
                 + S1c * (hx[((CP) + 2) & 7] + hx[((CP) + 6) & 7])              \
                 + S0c * (hx[((CP) + 3) & 7] + hx[((CP) + 5) & 7]);             \
        float gy = A3c * (hy[((CP) + 1) & 7] - hy[((CP) + 7) & 7])              \
                 + A2c * (hy[((CP) + 2) & 7] - hy[((CP) + 6) & 7])              \
                 + A1c * (hy[((CP) + 3) & 7] - hy[((CP) + 5) & 7]);             \
        mv = (okm) ? (gx * gx + gy * gy + 1e-12f) : 0.f;                        \
        mvL = dpp_shr1(mv);                                                     \
        mvR = dpp_shl1(mv);                                                     \
        float ax = fabsf(gx), ay = fabsf(gy);                                   \
        dv = (ay <= 0.4142135623730951f * ax) ? 0                               \
           : (ay >= 2.414213562373095f * ax) ? 2                                \
           : (((gx > 0.f) == (gy > 0.f)) ? 1 : 3);                              \
    }

    LOADPAIR(0);

    // ---- prime: pairs 0..2 fill ring slots 0..5 (gray rows 0..5) ----
#define PRIME(kk)                                                               \
    {                                                                           \
        float ga = 0.299f * r0 + 0.587f * g0c + 0.114f * b0;                    \
        float gb = 0.299f * r1 + 0.587f * g1c + 0.114f * b1;                    \
        LOADPAIR((kk) + 1);                                                     \
        HPUSH_AT(ga, 2 * (kk));                                                 \
        HPUSH_AT(gb, 2 * (kk) + 1);                                             \
    }
    PRIME(0); PRIME(1); PRIME(2);
#undef PRIME

    // pair 3: gray rows 6,7 -> mag rows y0-1, y0
    float mm1, mm1L, mm1R, m0, m0L, m0R;
    int dir0;
    {
        float ga = 0.299f * r0 + 0.587f * g0c + 0.114f * b0;
        float gb = 0.299f * r1 + 0.587f * g1c + 0.114f * b1;
        LOADPAIR(4);
        int dtmp;
        HPUSH_AT(ga, 6);
        MAG_AT(3, colok && (y0 > 0), mm1, mm1L, mm1R, dtmp);   // row y0-1
        (void)dtmp;
        HPUSH_AT(gb, 7);
        MAG_AT(4, colok, m0, m0L, m0R, dir0);                  // row y0
    }

    // ---- steady step: jj = k&3 literal (ring positions), k = pair index ----
#define STEP(jj, k, DOPREF)                                                     \
    {                                                                           \
        float ga = 0.299f * r0 + 0.587f * g0c + 0.114f * b0;                    \
        float gb = 0.299f * r1 + 0.587f * g1c + 0.114f * b1;                    \
        if (DOPREF) LOADPAIR((k) + 1);                                          \
        float ma, maL, maR, mb, mbL, mbR;                                       \
        int da, db;                                                             \
        HPUSH_AT(ga, 2 * (jj));                                                 \
        MAG_AT((2 * (jj) + 5) & 7, colok, ma, maL, maR, da);   /* row y0+2k-7 */\
        HPUSH_AT(gb, 2 * (jj) + 1);                                             \
        MAG_AT((2 * (jj) + 6) & 7, colok && (y0 + 2 * (k) - 6 < H),             \
               mb, mbL, mbR, db);                              /* row y0+2k-6 */\
        /* row t0: mags (mm1, m0, ma), dir0 */                                  \
        float n1 = (dir0 == 0) ? m0R : (dir0 == 1) ? maR : (dir0 == 2) ? ma : maL; \
        float n2 = (dir0 == 0) ? m0L : (dir0 == 1) ? mm1L : (dir0 == 2) ? mm1 : mm1R; \
        bool ok0 = (m0 >= n1) && (m0 >= n2);                                    \
        u64 bs0 = __ballot(ok0 && (m0 >= 0.04f));                               \
        u64 bw0 = __ballot(ok0 && (m0 >= 0.01f));                               \
        /* row t1: mags (m0, ma, mb), dir = da */                               \
        float n3 = (da == 0) ? maR : (da == 1) ? mbR : (da == 2) ? mb : mbL;    \
        float n4 = (da == 0) ? maL : (da == 1) ? m0L : (da == 2) ? m0 : m0R;    \
        bool ok1 = (ma >= n3) && (ma >= n4);                                    \
        u64 bs1 = __ballot(ok1 && (ma >= 0.04f));                               \
        u64 bw1 = __ballot(ok1 && (ma >= 0.01f));                               \
        if (lane == 0) {                                                        \
            int t0 = y0 + 2 * (k) - 8;                                          \
            ulonglong2 vs, vw;                                                  \
            vs.x = (bs0 >> 4) & omask; vs.y = (bs1 >> 4) & omask;               \
            vw.x = (bw0 >> 4) & omask; vw.y = (bw1 >> 4) & omask;               \
            *(ulonglong2*)&strongP[outBase + t0] = vs;                          \
            *(ulonglong2*)&weakP[outBase + t0] = vw;                            \
        }                                                                       \
        mm1 = ma; mm1L = maL; mm1R = maR;                                       \
        m0 = mb; m0L = mbL; m0R = mbR;                                          \
        dir0 = db;                                                              \
    }

#pragma unroll 1
    for (int k4 = 4; k4 < 16; k4 += 4) {
        STEP(0, k4 + 0, true);
        STEP(1, k4 + 1, true);
        STEP(2, k4 + 2, true);
        STEP(3, k4 + 3, true);
    }
    // tail: k = 16..19, last pair has no prefetch
    STEP(0, 16, true);
    STEP(1, 17, true);
    STEP(2, 18, true);
    STEP(3, 19, false);

#undef STEP
#undef MAG_AT
#undef HPUSH_AT
#undef LOADPAIR
}

// ---------------------------------------------------------------------------
// Kernel 2: bit-parallel hysteresis (10 iters, exact via light cone) + diff
// count + fused final reduction (atomic counter + ticket, last block writes).
// One wave per 32x32 tile per image-pair; lane l = row ty0-10+l.
// Loads from 56-bit strip words via 3-word funnel shift (coalesced: lane=y).
// ---------------------------------------------------------------------------
__device__ __forceinline__ u64 ldw10(const u64* p, int img, int y, int q, bool ok) {
    return (ok && q >= 0 && q < NSTRIP) ? p[((size_t)img * NSTRIP + q) * H + y] : 0ULL;
}

__global__ __launch_bounds__(256) void k_hyst(const u64* __restrict__ strongP,
                                              const u64* __restrict__ weakP,
                                              unsigned int* __restrict__ counters,
                                              float* __restrict__ out) {
    __shared__ unsigned int part[4];
    const int wy = threadIdx.x >> 6;
    const int wave = blockIdx.x * 4 + wy;
    const int lane = threadIdx.x & 63;
    const int tile = wave & 255;
    const int pair = wave >> 8;          // 0..15
    const int tx0 = (tile & 15) * 32;
    const int ty0 = (tile >> 4) * 32;

    const int y = ty0 - 10 + lane;
    const bool rowok = (lane < 52) && (y >= 0) && (y < H);
    const int yc = rowok ? y : 0;

    const int x = tx0 - 10;
    const int q0 = (x < 0) ? -1 : (x / 56);
    const int r = x - 56 * q0;           // 1..55, never 0
    const int sh1 = 56 - r;
    const bool need3 = (r > 48);
    const int sh2 = 112 - r;

    const int imgA = pair, imgB = pair + 16;
    u64 sA, wA, sB, wB;
    {
        u64 w0, w1, w2;
        w0 = ldw10(strongP, imgA, yc, q0, rowok);
        w1 = ldw10(strongP, imgA, yc, q0 + 1, rowok);
        w2 = need3 ? ldw10(strongP, imgA, yc, q0 + 2, rowok) : 0ULL;
        sA = (w0 >> r) | (w1 << sh1) | (need3 ? (w2 << sh2) : 0ULL);
        w0 = ldw10(weakP, imgA, yc, q0, rowok);
        w1 = ldw10(weakP, imgA, yc, q0 + 1, rowok);
        w2 = need3 ? ldw10(weakP, imgA, yc, q0 + 2, rowok) : 0ULL;
        wA = (w0 >> r) | (w1 << sh1) | (need3 ? (w2 << sh2) : 0ULL);
        w0 = ldw10(strongP, imgB, yc, q0, rowok);
        w1 = ldw10(strongP, imgB, yc, q0 + 1, rowok);
        w2 = need3 ? ldw10(strongP, imgB, yc, q0 + 2, rowok) : 0ULL;
        sB = (w0 >> r) | (w1 << sh1) | (need3 ? (w2 << sh2) : 0ULL);
        w0 = ldw10(weakP, imgB, yc, q0, rowok);
        w1 = ldw10(weakP, imgB, yc, q0 + 1, rowok);
        w2 = need3 ? ldw10(weakP, imgB, yc, q0 + 2, rowok) : 0ULL;
        wB = (w0 >> r) | (w1 << sh1) | (need3 ? (w2 << sh2) : 0ULL);
    }

#pragma unroll
    for (int it = 0; it < 10; it++) {
        u64 up = __shfl_up(sA, 1), dn = __shfl_down(sA, 1);
        u64 t = up | sA | dn;
        sA |= (t | (t << 1) | (t >> 1)) & wA;
        up = __shfl_up(sB, 1); dn = __shfl_down(sB, 1);
        t = up | sB | dn;
        sB |= (t | (t << 1) | (t >> 1)) & wB;
    }

    unsigned int cgt = 0;
    if (lane >= 10 && lane < 42) {
        const u64 mask = ((1ULL << 42) - (1ULL << 10));
        cgt = (unsigned int)__popcll((sA ^ sB) & mask);
    }
#pragma unroll
    for (int off = 32; off > 0; off >>= 1) cgt += __shfl_down(cgt, off);
    if (lane == 0) part[wy] = cgt;
    __syncthreads();
    if (threadIdx.x == 0) {
        unsigned int tot = part[0] + part[1] + part[2] + part[3];
        atomicAdd(&counters[0], tot);
        __threadfence();
        unsigned int t = atomicAdd(&counters[1], 1u);
        if (t == NHYST_BLK - 1) {
            unsigned int total = atomicAdd(&counters[0], 0u);  // all adds visible
            out[0] = (float)total * (1.0f / 4194304.0f);
        }
    }
}

extern "C" void kernel_launch(void* const* d_in, const int* in_sizes, int n_in,
                              void* d_out, int out_size, void* d_ws, size_t ws_size,
                              hipStream_t stream) {
    const float* yhat = (const float*)d_in[0];
    const float* yy = (const float*)d_in[1];

    u64* strongP = (u64*)d_ws;                        // 32*10*512 u64 = 1.31 MB
    u64* weakP = strongP + (size_t)NIMG * NSTRIP * H; // 1.31 MB
    unsigned int* counters = (unsigned int*)(weakP + (size_t)NIMG * NSTRIP * H);

    // 32 img x 10 strips x 16 bands = 5120 waves, 4 waves/block, 5 blk/CU
    k_edges<<<1280, 256, 0, stream>>>(yhat, yy, strongP, weakP, counters);

    // 256 tiles x 16 pairs = 4096 waves, 4 waves/block; fused finalize
    k_hyst<<<1024, 256, 0, stream>>>(strongP, weakP, counters, (float*)d_out);
}